// Round 4
// baseline (163.315 us; speedup 1.0000x reference)
//
#include <hip/hip_runtime.h>
#include <math.h>

// NetVLAD on MI355X via bf16 hi/lo-split MFMA (3-product emulated fp32).
// N=128 images, C=256 channels, K=64 clusters, P=1024 pixels.
// Block = (image, eighth): 128 pixels, 256 threads = 4 waves, 1024 blocks
//   -> 4 blocks/CU resident (34 KB LDS, <=128 VGPR), 16 waves/CU.
// GEMM1: logits[64k x 128p] = W[64k x 256c] @ x[256c x 128p]   (raw x; rn folded later)
// GEMM2: agg[64k x 256c]   += a[64k x 128p] @ (x*rn)^T[128p x 256c]
// MFMA 16x16x32 bf16: A row=lane&15, k=(lane>>4)*8+j; B col=lane&15, same k;
//                     C col=lane&15, row=(lane>>4)*4+reg   (verified in R2)

#define EPSF 1e-12f
#define BUF_LD 132     // u32 row stride for the 64 x 128 logits/a buffer

typedef __attribute__((ext_vector_type(8))) __bf16 bf16x8;
typedef __attribute__((ext_vector_type(4))) float f32x4;
typedef __attribute__((ext_vector_type(4))) unsigned int u32x4;

#define MFMA(a, b, c) __builtin_amdgcn_mfma_f32_16x16x32_bf16((a), (b), (c), 0, 0, 0)

__device__ __forceinline__ bf16x8 as_bf(u32x4 v) { return __builtin_bit_cast(bf16x8, v); }

// truncation split: x = hi + lo + O(2^-16 |x|), hi/lo bf16 (packed pairs)
__device__ __forceinline__ void split8(const float* xv, u32x4& hi, u32x4& lo) {
    unsigned uh[8], ul[8];
    #pragma unroll
    for (int j = 0; j < 8; ++j) {
        const unsigned u = __float_as_uint(xv[j]);
        uh[j] = u;
        const float hif = __uint_as_float(u & 0xFFFF0000u);
        ul[j] = __float_as_uint(xv[j] - hif);
    }
    #pragma unroll
    for (int w = 0; w < 4; ++w) {
        hi[w] = (uh[2*w+1] & 0xFFFF0000u) | (uh[2*w] >> 16);
        lo[w] = (ul[2*w+1] & 0xFFFF0000u) | (ul[2*w] >> 16);
    }
}

__global__ __launch_bounds__(256, 4) void netvlad_mfma(
    const float* __restrict__ x, const float* __restrict__ wmat,
    const float* __restrict__ bias, float* __restrict__ out,
    float* __restrict__ asum_g) {

    __shared__ __align__(16) unsigned int buf[64 * BUF_LD];   // logits f32 -> packed a
    __shared__ __align__(16) float rn_lds[128];
    __shared__ float bias_lds[64];
    float* buf_f = (float*)buf;

    const int t = threadIdx.x;
    const int w = t >> 6, l = t & 63;
    const int l15 = l & 15, lg4 = l >> 4;
    const int n = blockIdx.x >> 3, e = blockIdx.x & 7;
    const size_t ximg = (size_t)n * 256 * 1024;
    const int p0 = e * 128;
    const int k0 = w * 16;                // wave owns k-rows k0..k0+15
    const int cs = lg4 * 8;               // k-slice base within a 32-wide K-step

    if (t < 64) bias_lds[t] = bias[t];

    // ---- W fragments (GEMM1 A), loaded once into registers: 64 VGPRs
    u32x4 whi[8], wlo[8];
    {
        const float* wr = wmat + (k0 + l15) * 256 + cs;
        #pragma unroll
        for (int ks = 0; ks < 8; ++ks) {
            float xv[8];
            const float4 f0 = *(const float4*)(wr + ks * 32);
            const float4 f1 = *(const float4*)(wr + ks * 32 + 4);
            xv[0]=f0.x; xv[1]=f0.y; xv[2]=f0.z; xv[3]=f0.w;
            xv[4]=f1.x; xv[5]=f1.y; xv[6]=f1.z; xv[7]=f1.w;
            split8(xv, whi[ks], wlo[ks]);
        }
    }

    // ---- GEMM1: raw logits (8 pixel-tiles of 16)
    f32x4 acc[8];
    #pragma unroll
    for (int i = 0; i < 8; ++i) acc[i] = f32x4{0.f, 0.f, 0.f, 0.f};
    float ssp[8];
    #pragma unroll
    for (int i = 0; i < 8; ++i) ssp[i] = 0.f;
    const bool ss_wave = (w == 0);        // wave 0 also accumulates sum(x^2)

    for (int ks = 0; ks < 8; ++ks) {
        #pragma unroll
        for (int nt = 0; nt < 8; ++nt) {
            // B frag: x[c = ks*32+cs+j][p = p0 + nt*16 + l15], 8 strided dwords
            const float* bp = x + ximg + (size_t)(ks * 32 + cs) * 1024
                              + p0 + nt * 16 + l15;
            float xv[8];
            #pragma unroll
            for (int j = 0; j < 8; ++j) xv[j] = bp[(size_t)j * 1024];
            if (ss_wave) {
                #pragma unroll
                for (int j = 0; j < 8; ++j) ssp[nt] = fmaf(xv[j], xv[j], ssp[nt]);
            }
            u32x4 bhi, blo; split8(xv, bhi, blo);
            acc[nt] = MFMA(as_bf(whi[ks]), as_bf(bhi), acc[nt]);
            acc[nt] = MFMA(as_bf(whi[ks]), as_bf(blo), acc[nt]);
            acc[nt] = MFMA(as_bf(wlo[ks]), as_bf(bhi), acc[nt]);
        }
    }

    // write raw logits to LDS (stride 132: 2-way worst case = free)
    #pragma unroll
    for (int nt = 0; nt < 8; ++nt) {
        const int pp = nt * 16 + l15;
        #pragma unroll
        for (int r = 0; r < 4; ++r)
            buf_f[(k0 + lg4 * 4 + r) * BUF_LD + pp] = acc[nt][r];
    }
    // rn[p] = 1/max(sqrt(ss),eps): wave 0 covers all 128 pixels
    if (ss_wave) {
        #pragma unroll
        for (int nt = 0; nt < 8; ++nt) {
            float s = ssp[nt];
            s += __shfl_xor(s, 16);
            s += __shfl_xor(s, 32);
            if (l < 16) rn_lds[nt * 16 + l] = 1.f / fmaxf(sqrtf(s), EPSF);
        }
    }
    __syncthreads();

    // ---- softmax: one pixel per thread (t<128); columns are thread-private
    if (t < 128) {
        const float rn = rn_lds[t];
        float a[64];
        #pragma unroll
        for (int k = 0; k < 64; ++k)
            a[k] = fmaf(buf_f[k * BUF_LD + t], rn, bias_lds[k]);
        float mx = -3.402823466e38f;
        #pragma unroll
        for (int k = 0; k < 64; ++k) mx = fmaxf(mx, a[k]);
        float den = 0.f;
        #pragma unroll
        for (int k = 0; k < 64; ++k) { a[k] = __expf(a[k] - mx); den += a[k]; }
        const float inv = 1.f / den;
        #pragma unroll
        for (int k = 0; k < 64; ++k) {
            const float v = a[k] * inv;              // raw a (rn applied to B later)
            const unsigned u  = __float_as_uint(v);
            const float hif   = __uint_as_float(u & 0xFFFF0000u);
            const unsigned lo = __float_as_uint(v - hif) >> 16;
            buf[k * BUF_LD + t] = (u & 0xFFFF0000u) | lo;   // (hi<<16)|lo
        }
    }
    __syncthreads();

    // ---- GEMM2: agg += a @ (x*rn)^T ; asum via MFMA with ones-B
    f32x4 acc2[16];
    #pragma unroll
    for (int i = 0; i < 16; ++i) acc2[i] = f32x4{0.f, 0.f, 0.f, 0.f};
    f32x4 asum_acc = f32x4{0.f, 0.f, 0.f, 0.f};
    const u32x4 ONES = {0x3F803F80u, 0x3F803F80u, 0x3F803F80u, 0x3F803F80u};

    for (int ks = 0; ks < 4; ++ks) {
        // A frag: packed a at [k = k0+l15][p = ks*32+cs+j], contiguous 8 dwords
        const unsigned* ap = buf + (k0 + l15) * BUF_LD + ks * 32 + cs;
        const u32x4 pa = *(const u32x4*)ap;
        const u32x4 pb = *(const u32x4*)(ap + 4);
        u32x4 ahi, alo;
        ahi[0] = (pa[1] & 0xFFFF0000u) | (pa[0] >> 16);
        ahi[1] = (pa[3] & 0xFFFF0000u) | (pa[2] >> 16);
        ahi[2] = (pb[1] & 0xFFFF0000u) | (pb[0] >> 16);
        ahi[3] = (pb[3] & 0xFFFF0000u) | (pb[2] >> 16);
        alo[0] = (pa[1] << 16) | (pa[0] & 0xFFFFu);
        alo[1] = (pa[3] << 16) | (pa[2] & 0xFFFFu);
        alo[2] = (pb[1] << 16) | (pb[0] & 0xFFFFu);
        alo[3] = (pb[3] << 16) | (pb[2] & 0xFFFFu);

        const float* rp = rn_lds + ks * 32 + cs;
        const f32x4 r0 = *(const f32x4*)rp;
        const f32x4 r1 = *(const f32x4*)(rp + 4);
        const float rnv[8] = {r0[0], r0[1], r0[2], r0[3], r1[0], r1[1], r1[2], r1[3]};

        asum_acc = MFMA(as_bf(ahi), as_bf(ONES), asum_acc);
        asum_acc = MFMA(as_bf(alo), as_bf(ONES), asum_acc);

        #pragma unroll
        for (int nt = 0; nt < 16; ++nt) {
            // B frag: x[c = nt*16+l15][p = p0 + ks*32+cs+j] * rn, contiguous 32B
            const float* xp2 = x + ximg + (size_t)(nt * 16 + l15) * 1024
                               + p0 + ks * 32 + cs;
            const float4 f0 = *(const float4*)xp2;
            const float4 f1 = *(const float4*)(xp2 + 4);
            float xv[8];
            xv[0] = f0.x * rnv[0]; xv[1] = f0.y * rnv[1];
            xv[2] = f0.z * rnv[2]; xv[3] = f0.w * rnv[3];
            xv[4] = f1.x * rnv[4]; xv[5] = f1.y * rnv[5];
            xv[6] = f1.z * rnv[6]; xv[7] = f1.w * rnv[7];
            u32x4 bhi, blo; split8(xv, bhi, blo);
            acc2[nt] = MFMA(as_bf(ahi), as_bf(bhi), acc2[nt]);
            acc2[nt] = MFMA(as_bf(ahi), as_bf(blo), acc2[nt]);
            acc2[nt] = MFMA(as_bf(alo), as_bf(bhi), acc2[nt]);
        }
    }

    // ---- publish partials (8 eighth-blocks per image)
    float* op = out + (size_t)n * 16384;
    #pragma unroll
    for (int nt = 0; nt < 16; ++nt) {
        const int c = nt * 16 + l15;
        #pragma unroll
        for (int r = 0; r < 4; ++r)
            atomicAdd(&op[(k0 + lg4 * 4 + r) * 256 + c], acc2[nt][r]);
    }
    if (l15 == 0) {
        #pragma unroll
        for (int r = 0; r < 4; ++r)
            atomicAdd(&asum_g[n * 64 + k0 + lg4 * 4 + r], asum_acc[r]);
    }
}

__global__ __launch_bounds__(256) void netvlad_epi(
    float* __restrict__ out, const float* __restrict__ asum_g,
    const float* __restrict__ cent) {
    __shared__ float wred[4];
    __shared__ float gs_sh;
    const int n = blockIdx.x;
    const int t = threadIdx.x;
    const int k = t >> 2;          // 4 threads per cluster row
    const int q = t & 3;
    float* op = out + (size_t)n * 16384 + k * 256 + q * 64;
    const float* cp = cent + k * 256 + q * 64;
    const float as = asum_g[n * 64 + k];

    float v[64];
    float ss = 0.f;
    #pragma unroll
    for (int i = 0; i < 64; i += 4) {
        const float4 av = *(const float4*)&op[i];
        const float4 cv = *(const float4*)&cp[i];
        v[i+0] = fmaf(-as, cv.x, av.x);
        v[i+1] = fmaf(-as, cv.y, av.y);
        v[i+2] = fmaf(-as, cv.z, av.z);
        v[i+3] = fmaf(-as, cv.w, av.w);
        ss = fmaf(v[i+0], v[i+0], ss);
        ss = fmaf(v[i+1], v[i+1], ss);
        ss = fmaf(v[i+2], v[i+2], ss);
        ss = fmaf(v[i+3], v[i+3], ss);
    }
    // intra-norm: reduce over the 4 lanes sharing k
    ss += __shfl_xor(ss, 1);
    ss += __shfl_xor(ss, 2);
    const float iscale = 1.f / fmaxf(sqrtf(ss), EPSF);

    // global norm: sum of ss*iscale^2 over distinct k rows
    float g = (q == 0) ? ss * iscale * iscale : 0.f;
    #pragma unroll
    for (int off = 4; off < 64; off <<= 1) g += __shfl_xor(g, off);
    if ((t & 63) == 0) wred[t >> 6] = g;
    __syncthreads();
    if (t == 0) {
        const float tot = wred[0] + wred[1] + wred[2] + wred[3];
        gs_sh = 1.f / fmaxf(sqrtf(tot), EPSF);
    }
    __syncthreads();
    const float fs = iscale * gs_sh;
    #pragma unroll
    for (int i = 0; i < 64; i += 4) {
        float4 w4;
        w4.x = v[i+0] * fs; w4.y = v[i+1] * fs;
        w4.z = v[i+2] * fs; w4.w = v[i+3] * fs;
        *(float4*)&op[i] = w4;
    }
}

extern "C" void kernel_launch(void* const* d_in, const int* in_sizes, int n_in,
                              void* d_out, int out_size, void* d_ws, size_t ws_size,
                              hipStream_t stream) {
    (void)in_sizes; (void)n_in; (void)ws_size;
    const float* x    = (const float*)d_in[0];
    const float* w    = (const float*)d_in[1];
    const float* b    = (const float*)d_in[2];
    const float* cent = (const float*)d_in[3];
    float* out    = (float*)d_out;
    float* asum_g = (float*)d_ws;          // 8192 floats

    hipMemsetAsync(d_out, 0, (size_t)out_size * sizeof(float), stream);
    hipMemsetAsync(asum_g, 0, 128 * 64 * sizeof(float), stream);
    netvlad_mfma<<<1024, 256, 0, stream>>>(x, w, b, out, asum_g);
    netvlad_epi<<<128, 256, 0, stream>>>(out, asum_g, cent);
}

// Round 5
// 113.620 us; speedup vs baseline: 1.4374x; 1.4374x over previous
//
#include <hip/hip_runtime.h>
#include <math.h>

// NetVLAD on MI355X via bf16 hi/lo-split MFMA, LDS-staged slabs.
// N=128 images, C=256 channels, K=64 clusters, P=1024 pixels.
// Block = (image, eighth): 128 pixels, 256 threads = 4 waves, 1024 blocks.
// x staged per 32-channel slab into LDS as packed (hi16|lo16) bf16 split,
// double-buffered; GEMM1 and GEMM2 read fragments from LDS only.
// GEMM1: logits[64k x 128p] = W @ x_raw            (rn folded into softmax)
// GEMM2: agg[64k x 256c]   += (a*rn) @ x_raw^T     (rn folded into A side)
// MFMA 16x16x32 bf16 layouts as verified in R2/R3.

#define EPSF 1e-12f
#define XS_LD 129      // u32 slab row stride: GEMM1/GEMM2 reads <=2-way banks
#define BUF_LD 132     // u32/f32 stride for logits/a buffer

typedef __attribute__((ext_vector_type(8))) __bf16 bf16x8;
typedef __attribute__((ext_vector_type(4))) float f32x4;
typedef __attribute__((ext_vector_type(4))) unsigned int u32x4;

#define MFMA(a, b, c) __builtin_amdgcn_mfma_f32_16x16x32_bf16((a), (b), (c), 0, 0, 0)

__device__ __forceinline__ bf16x8 as_bf(u32x4 v) { return __builtin_bit_cast(bf16x8, v); }

// f32 -> packed (hi_bf16 << 16) | lo_bf16  (truncation split, err ~2^-16|x|)
__device__ __forceinline__ unsigned packsplit(float x) {
    const unsigned u  = __float_as_uint(x);
    const unsigned hi = u & 0xFFFF0000u;
    const float lof   = x - __uint_as_float(hi);
    return hi | (__float_as_uint(lof) >> 16);
}

// 8 packed u32 -> (hi,lo) MFMA operand pair, 2 v_perm per word
__device__ __forceinline__ void unpack8(const unsigned* p, u32x4& hi, u32x4& lo) {
    #pragma unroll
    for (int w2 = 0; w2 < 4; ++w2) {
        hi[w2] = __builtin_amdgcn_perm(p[2*w2+1], p[2*w2], 0x07060302u);
        lo[w2] = __builtin_amdgcn_perm(p[2*w2+1], p[2*w2], 0x05040100u);
    }
}

__device__ __forceinline__ void split8v(const float* xv, u32x4& hi, u32x4& lo) {
    unsigned uh[8], ul[8];
    #pragma unroll
    for (int j = 0; j < 8; ++j) {
        const unsigned u = __float_as_uint(xv[j]);
        uh[j] = u;
        const float hif = __uint_as_float(u & 0xFFFF0000u);
        ul[j] = __float_as_uint(xv[j] - hif);
    }
    #pragma unroll
    for (int w2 = 0; w2 < 4; ++w2) {
        hi[w2] = (uh[2*w2+1] & 0xFFFF0000u) | (uh[2*w2] >> 16);
        lo[w2] = (ul[2*w2+1] & 0xFFFF0000u) | (ul[2*w2] >> 16);
    }
}

__global__ __launch_bounds__(256, 2) void netvlad_mfma(
    const float* __restrict__ x, const float* __restrict__ wmat,
    const float* __restrict__ bias, float* __restrict__ out,
    float* __restrict__ asum_g) {

    __shared__ __align__(16) unsigned xs[2][32 * XS_LD];   // split-x slab dbuf
    __shared__ __align__(16) unsigned buf[64 * BUF_LD];    // logits f32 -> packed a
    __shared__ float sspart[256];
    __shared__ float rn_lds[128];
    __shared__ float bias_lds[64];
    float* buf_f = (float*)buf;

    const int t = threadIdx.x;
    const int w = t >> 6, l = t & 63;
    const int l15 = l & 15, lg4 = l >> 4;
    const int n = blockIdx.x >> 3, e = blockIdx.x & 7;
    const size_t ximg = (size_t)n * 256 * 1024;
    const int p0 = e * 128;
    const int k0 = w * 16;                 // wave owns k-rows k0..k0+15
    const int cs = lg4 * 8;                // k-slice base within a 32-wide K-step

    // staging ownership: thread stages rows {srow+8i}, pixel quad sq4
    const int srow = t >> 5;
    const int sq4  = (t & 31) * 4;
    const float* xbase = x + ximg + (size_t)srow * 1024 + p0 + sq4;
    const int stoff = srow * XS_LD + sq4;

    if (t < 64) bias_lds[t] = bias[t];

    // ---- W fragments (GEMM1 A), resident for pass 1: 64 VGPRs
    u32x4 whi[8], wlo[8];
    {
        const float* wr = wmat + (k0 + l15) * 256 + cs;
        #pragma unroll
        for (int ks = 0; ks < 8; ++ks) {
            float xv[8];
            const float4 f0 = *(const float4*)(wr + ks * 32);
            const float4 f1 = *(const float4*)(wr + ks * 32 + 4);
            xv[0]=f0.x; xv[1]=f0.y; xv[2]=f0.z; xv[3]=f0.w;
            xv[4]=f1.x; xv[5]=f1.y; xv[6]=f1.z; xv[7]=f1.w;
            split8v(xv, whi[ks], wlo[ks]);
        }
    }

    float4 g[4];
    #define STAGE_ISSUE(c0_) {                                              \
        _Pragma("unroll")                                                   \
        for (int i = 0; i < 4; ++i)                                         \
            g[i] = *(const float4*)(xbase + (size_t)((c0_) + 8*i) * 1024);  \
    }
    #define STAGE_WRITE(b_) {                                               \
        unsigned* dstb = &xs[(b_)][stoff];                                  \
        _Pragma("unroll")                                                   \
        for (int i = 0; i < 4; ++i) {                                       \
            unsigned* d2 = dstb + i * 8 * XS_LD;                            \
            d2[0] = packsplit(g[i].x); d2[1] = packsplit(g[i].y);           \
            d2[2] = packsplit(g[i].z); d2[3] = packsplit(g[i].w);           \
        }                                                                   \
    }

    // ================= PASS 1: logits + ss =================
    f32x4 acc[8];
    #pragma unroll
    for (int i = 0; i < 8; ++i) acc[i] = f32x4{0.f, 0.f, 0.f, 0.f};
    float ssacc = 0.f;
    const int ss_p = t & 127;                 // pixel this thread reduces
    const int ss_c = (t >> 7) * 16;           // half of the slab's rows

    STAGE_ISSUE(0);
    STAGE_WRITE(0);
    #pragma unroll
    for (int s = 0; s < 8; ++s) {
        if (s < 7) STAGE_ISSUE((s + 1) * 32);
        __syncthreads();
        const unsigned* sb = xs[s & 1];
        #pragma unroll
        for (int nt = 0; nt < 8; ++nt) {
            unsigned pw[8];
            #pragma unroll
            for (int j = 0; j < 8; ++j)
                pw[j] = sb[(cs + j) * XS_LD + nt * 16 + l15];
            u32x4 bhi, blo; unpack8(pw, bhi, blo);
            acc[nt] = MFMA(as_bf(whi[s]), as_bf(bhi), acc[nt]);
            acc[nt] = MFMA(as_bf(whi[s]), as_bf(blo), acc[nt]);
            acc[nt] = MFMA(as_bf(wlo[s]), as_bf(bhi), acc[nt]);
        }
        {   // ss partial: reconstruct x from split, accumulate x^2
            const unsigned* col = sb + ss_c * XS_LD + ss_p;
            #pragma unroll
            for (int cl = 0; cl < 16; ++cl) {
                const unsigned u = col[cl * XS_LD];
                const float v = __uint_as_float(u & 0xFFFF0000u)
                              + __uint_as_float(u << 16);
                ssacc = fmaf(v, v, ssacc);
            }
        }
        if (s < 7) STAGE_WRITE((s + 1) & 1);
    }
    sspart[t] = ssacc;

    // write raw logits to buf (banks: 16lg4 pattern -> 2-way, free)
    #pragma unroll
    for (int nt = 0; nt < 8; ++nt) {
        const int pp = nt * 16 + l15;
        #pragma unroll
        for (int r = 0; r < 4; ++r)
            buf_f[(k0 + lg4 * 4 + r) * BUF_LD + pp] = acc[nt][r];
    }
    __syncthreads();

    // ---- softmax: one pixel per thread (t<128)
    if (t < 128) {
        const float ssv = sspart[t] + sspart[t + 128];
        const float rn = 1.f / fmaxf(sqrtf(ssv), EPSF);
        rn_lds[t] = rn;
        float a[64];
        #pragma unroll
        for (int k = 0; k < 64; ++k)
            a[k] = fmaf(buf_f[k * BUF_LD + t], rn, bias_lds[k]);
        float mx = -3.402823466e38f;
        #pragma unroll
        for (int k = 0; k < 64; ++k) mx = fmaxf(mx, a[k]);
        float den = 0.f;
        #pragma unroll
        for (int k = 0; k < 64; ++k) { a[k] = __expf(a[k] - mx); den += a[k]; }
        const float inv = 1.f / den;
        #pragma unroll
        for (int k = 0; k < 64; ++k)
            buf[k * BUF_LD + t] = packsplit(a[k] * inv);   // raw a, packed split
    }
    __syncthreads();

    // ---- A-frags for GEMM2: raw a (asum) + a*rn resplit (agg); 4 ks frags
    u32x4 aphi[4], aplo[4];
    f32x4 asum_acc = f32x4{0.f, 0.f, 0.f, 0.f};
    const u32x4 ONES = {0x3F803F80u, 0x3F803F80u, 0x3F803F80u, 0x3F803F80u};
    #pragma unroll
    for (int ks = 0; ks < 4; ++ks) {
        unsigned pa[8];
        #pragma unroll
        for (int j = 0; j < 8; ++j)
            pa[j] = buf[(k0 + l15) * BUF_LD + ks * 32 + cs + j];
        u32x4 ahi, alo; unpack8(pa, ahi, alo);
        asum_acc = MFMA(as_bf(ahi), as_bf(ONES), asum_acc);
        asum_acc = MFMA(as_bf(alo), as_bf(ONES), asum_acc);
        // a' = a*rn, resplit (amortized over 16 N-tiles)
        const float* rp = rn_lds + ks * 32 + cs;
        float av[8];
        #pragma unroll
        for (int j = 0; j < 8; ++j) {
            const float af = __uint_as_float(pa[j] & 0xFFFF0000u)
                           + __uint_as_float(pa[j] << 16);
            av[j] = af * rp[j];
        }
        split8v(av, aphi[ks], aplo[ks]);
    }

    // ================= PASS 2: agg = a' @ x^T =================
    float* op = out + (size_t)n * 16384;
    STAGE_ISSUE(0);
    STAGE_WRITE(0);
    for (int s2 = 0; s2 < 8; ++s2) {
        if (s2 < 7) STAGE_ISSUE((s2 + 1) * 32);
        __syncthreads();
        const unsigned* sb = xs[s2 & 1];
        f32x4 a2[2];
        a2[0] = f32x4{0.f, 0.f, 0.f, 0.f};
        a2[1] = f32x4{0.f, 0.f, 0.f, 0.f};
        #pragma unroll
        for (int ntl = 0; ntl < 2; ++ntl) {
            #pragma unroll
            for (int ks = 0; ks < 4; ++ks) {
                unsigned pw[8];
                #pragma unroll
                for (int j = 0; j < 8; ++j)
                    pw[j] = sb[(ntl * 16 + l15) * XS_LD + ks * 32 + cs + j];
                u32x4 bhi, blo; unpack8(pw, bhi, blo);
                a2[ntl] = MFMA(as_bf(aphi[ks]), as_bf(bhi), a2[ntl]);
                a2[ntl] = MFMA(as_bf(aphi[ks]), as_bf(blo), a2[ntl]);
                a2[ntl] = MFMA(as_bf(aplo[ks]), as_bf(bhi), a2[ntl]);
            }
        }
        if (s2 < 7) STAGE_WRITE((s2 + 1) & 1);
        #pragma unroll
        for (int ntl = 0; ntl < 2; ++ntl) {
            const int c = (s2 * 2 + ntl) * 16 + l15;
            #pragma unroll
            for (int r = 0; r < 4; ++r)
                atomicAdd(&op[(k0 + lg4 * 4 + r) * 256 + c], a2[ntl][r]);
        }
    }
    if (l15 == 0) {
        #pragma unroll
        for (int r = 0; r < 4; ++r)
            atomicAdd(&asum_g[n * 64 + k0 + lg4 * 4 + r], asum_acc[r]);
    }
}

__global__ __launch_bounds__(256) void netvlad_epi(
    float* __restrict__ out, const float* __restrict__ asum_g,
    const float* __restrict__ cent) {
    __shared__ float wred[4];
    __shared__ float gs_sh;
    const int n = blockIdx.x;
    const int t = threadIdx.x;
    const int k = t >> 2;          // 4 threads per cluster row
    const int q = t & 3;
    float* op = out + (size_t)n * 16384 + k * 256 + q * 64;
    const float* cp = cent + k * 256 + q * 64;
    const float as = asum_g[n * 64 + k];

    float v[64];
    float ss = 0.f;
    #pragma unroll
    for (int i = 0; i < 64; i += 4) {
        const float4 av = *(const float4*)&op[i];
        const float4 cv = *(const float4*)&cp[i];
        v[i+0] = fmaf(-as, cv.x, av.x);
        v[i+1] = fmaf(-as, cv.y, av.y);
        v[i+2] = fmaf(-as, cv.z, av.z);
        v[i+3] = fmaf(-as, cv.w, av.w);
        ss = fmaf(v[i+0], v[i+0], ss);
        ss = fmaf(v[i+1], v[i+1], ss);
        ss = fmaf(v[i+2], v[i+2], ss);
        ss = fmaf(v[i+3], v[i+3], ss);
    }
    ss += __shfl_xor(ss, 1);
    ss += __shfl_xor(ss, 2);
    const float iscale = 1.f / fmaxf(sqrtf(ss), EPSF);

    float gsum = (q == 0) ? ss * iscale * iscale : 0.f;
    #pragma unroll
    for (int off = 4; off < 64; off <<= 1) gsum += __shfl_xor(gsum, off);
    if ((t & 63) == 0) wred[t >> 6] = gsum;
    __syncthreads();
    if (t == 0) {
        const float tot = wred[0] + wred[1] + wred[2] + wred[3];
        gs_sh = 1.f / fmaxf(sqrtf(tot), EPSF);
    }
    __syncthreads();
    const float fs = iscale * gs_sh;
    #pragma unroll
    for (int i = 0; i < 64; i += 4) {
        float4 w4;
        w4.x = v[i+0] * fs; w4.y = v[i+1] * fs;
        w4.z = v[i+2] * fs; w4.w = v[i+3] * fs;
        *(float4*)&op[i] = w4;
    }
}

extern "C" void kernel_launch(void* const* d_in, const int* in_sizes, int n_in,
                              void* d_out, int out_size, void* d_ws, size_t ws_size,
                              hipStream_t stream) {
    (void)in_sizes; (void)n_in; (void)ws_size;
    const float* x    = (const float*)d_in[0];
    const float* w    = (const float*)d_in[1];
    const float* b    = (const float*)d_in[2];
    const float* cent = (const float*)d_in[3];
    float* out    = (float*)d_out;
    float* asum_g = (float*)d_ws;          // 8192 floats

    hipMemsetAsync(d_out, 0, (size_t)out_size * sizeof(float), stream);
    hipMemsetAsync(asum_g, 0, 128 * 64 * sizeof(float), stream);
    netvlad_mfma<<<1024, 256, 0, stream>>>(x, w, b, out, asum_g);
    netvlad_epi<<<128, 256, 0, stream>>>(out, asum_g, cent);
}